// Round 12
// baseline (88.993 us; speedup 1.0000x reference)
//
#include <hip/hip_runtime.h>

#define Bn 1024
#define Dn 512
#define Cn 512
#define KT 64           // k per staged B tile
#define NTL (Dn / KT)   // 8 tiles
#define NBLK 64         // grid size; all blocks co-resident (1 block/CU, 64 <= 256 CUs)

typedef __attribute__((ext_vector_type(8))) short s16x8;   // MFMA A/B frag (8 bf16)
typedef __attribute__((ext_vector_type(4))) float f32x4;   // MFMA C/D frag
typedef __attribute__((ext_vector_type(4))) unsigned short u16x4;
typedef __attribute__((ext_vector_type(8))) unsigned short u16x8;

__device__ __forceinline__ unsigned short f2bf(float f) {  // RNE f32->bf16
    unsigned u = __builtin_bit_cast(unsigned, f);
    u += 0x7FFF + ((u >> 16) & 1);
    return (unsigned short)(u >> 16);
}

// Single fused launch. Phase 1: W[k][c] fp32 -> wt[c][k] bf16 (this block's 64x64 tile).
// Grid barrier (device-scope atomics; counter CAS-initialized from the 0xAA poison).
// Phase 2: 16 samples x 512 cols staged-LDS MFMA GEMM + softmax-grad norm (verified R9).
__global__ __launch_bounds__(512) void gnorm_fused(
    const float* __restrict__ x,             // [B][D] fp32
    const float* __restrict__ W,             // [D][C] fp32
    const float* __restrict__ y,             // [B][C]
    const float* __restrict__ bias,          // [C]
    float* __restrict__ out,                 // [B]
    unsigned short* __restrict__ wt,         // [C][D] bf16 scratch (d_ws)
    unsigned* __restrict__ cnt)              // grid-barrier counter (d_ws, poisoned 0xAA)
{
    // smem layout: phase 2 needs Ab(16K)+Bb(128K)+reduce bufs; phase 1's lt overlays Ab.
    __shared__ __align__(16) char smem[16384 + 131072 + 3 * 512 + 64];
    unsigned short* Ab  = (unsigned short*)smem;            // 16 KB, row r at r*1024B, XOR (r&7)
    char*           BbC = smem + 16384;                     // 2 x 64 KB, row c at c*128B, XOR (c&7)
    float* lmax = (float*)(smem + 16384 + 131072);          // [16*8]
    float* lsum = lmax + 128;
    float* lgsq = lsum + 128;
    float* xn2s = lgsq + 128;

    const int tid = threadIdx.x;
    const int wv  = tid >> 6;        // 0..7
    const int l   = tid & 63;
    const int l15 = l & 15;
    const int lg  = l >> 4;          // 0..3
    const int s0  = blockIdx.x * 16;

    // Idempotent counter init from poison: exactly one CAS succeeds per call.
    if (tid == 0) atomicCAS(cnt, 0xAAAAAAAAu, 0u);

    // ---- Phase 1: transpose+convert this block's 64x64 W tile (verified wconv math) ----
    {
        auto lt = (unsigned short(*)[73])smem;   // [c_local][k_local], odd pad
        const int tb = blockIdx.x;               // 8x8 tiles of 64x64
        const int k0 = (tb >> 3) * 64, c0 = (tb & 7) * 64;
        const int rr = tid >> 4, cc = tid & 15;  // rr 0..31 with 512 threads
        #pragma unroll
        for (int p = 0; p < 2; ++p) {
            const int kl = rr + p * 32;
            float4 v = *(const float4*)&W[(size_t)(k0 + kl) * Cn + c0 + cc * 4];
            lt[cc * 4 + 0][kl] = f2bf(v.x);
            lt[cc * 4 + 1][kl] = f2bf(v.y);
            lt[cc * 4 + 2][kl] = f2bf(v.z);
            lt[cc * 4 + 3][kl] = f2bf(v.w);
        }
        __syncthreads();
        #pragma unroll
        for (int p = 0; p < 2; ++p) {
            const int cl = rr + p * 32;
            u16x4 o;
            o[0] = lt[cl][cc * 4 + 0]; o[1] = lt[cl][cc * 4 + 1];
            o[2] = lt[cl][cc * 4 + 2]; o[3] = lt[cl][cc * 4 + 3];
            *(u16x4*)&wt[(size_t)(c0 + cl) * Dn + k0 + cc * 4] = o;
        }
        __threadfence();     // make this thread's wt stores device-visible
        __syncthreads();     // all stores issued; also fences smem reuse (lt -> Ab)
    }

    // ---- A stage (independent of W: hides some barrier latency) ----
    {
        const int row = tid >> 5, cs = tid & 31;   // 16 fp32 per thread
        const float* xp = &x[(size_t)(s0 + row) * Dn + cs * 16];
        float4 v0 = *(const float4*)xp,       v1 = *(const float4*)(xp + 4);
        float4 v2 = *(const float4*)(xp + 8), v3 = *(const float4*)(xp + 12);
        float ss = v0.x*v0.x + v0.y*v0.y + v0.z*v0.z + v0.w*v0.w
                 + v1.x*v1.x + v1.y*v1.y + v1.z*v1.z + v1.w*v1.w
                 + v2.x*v2.x + v2.y*v2.y + v2.z*v2.z + v2.w*v2.w
                 + v3.x*v3.x + v3.y*v3.y + v3.z*v3.z + v3.w*v3.w;
        u16x8 o0, o1;
        o0[0]=f2bf(v0.x); o0[1]=f2bf(v0.y); o0[2]=f2bf(v0.z); o0[3]=f2bf(v0.w);
        o0[4]=f2bf(v1.x); o0[5]=f2bf(v1.y); o0[6]=f2bf(v1.z); o0[7]=f2bf(v1.w);
        o1[0]=f2bf(v2.x); o1[1]=f2bf(v2.y); o1[2]=f2bf(v2.z); o1[3]=f2bf(v2.w);
        o1[4]=f2bf(v3.x); o1[5]=f2bf(v3.y); o1[6]=f2bf(v3.z); o1[7]=f2bf(v3.w);
        char* base = (char*)Ab + row * 1024;
        *(u16x8*)(base + (((2*cs    ) ^ (row & 7)) << 4)) = o0;
        *(u16x8*)(base + (((2*cs + 1) ^ (row & 7)) << 4)) = o1;
        #pragma unroll
        for (int off = 1; off < 32; off <<= 1) ss += __shfl_xor(ss, off, 32);
        if ((tid & 31) == 0) xn2s[row] = ss;
    }

    // ---- Grid barrier: all 64 blocks' wt tiles visible before B staging ----
    if (tid == 0) {
        __hip_atomic_fetch_add(cnt, 1u, __ATOMIC_ACQ_REL, __HIP_MEMORY_SCOPE_AGENT);
        while (__hip_atomic_load(cnt, __ATOMIC_ACQUIRE, __HIP_MEMORY_SCOPE_AGENT) < NBLK)
            __builtin_amdgcn_s_sleep(2);
    }
    __syncthreads();

    // ---- B staging helper (verified R9): contiguous 16B global, swizzled LDS ----
    const int bc = (wv * 8) * 8 + (l >> 3);   // base c for this wave's instr 0
    const int kc = l & 7;                     // 16B chunk within 128B tile-row
    const int swz = (kc ^ (l >> 3)) << 4;     // (c&7) == l>>3 here
#define STAGE_B(kt_, b_)                                                        \
    {                                                                           \
        _Pragma("unroll")                                                       \
        for (int i = 0; i < 8; ++i) {                                           \
            const int c = bc + i * 8;                                           \
            u16x8 v = *(const u16x8*)&wt[(size_t)c * Dn + (kt_) * KT + kc * 8]; \
            *(u16x8*)(BbC + (b_) * (512 * KT * 2) + c * 128 + swz) = v;         \
        }                                                                       \
    }

    STAGE_B(0, 0);
    __syncthreads();

    // ---- K-loop: 8 tiles, double-buffered, single barrier per tile ----
    f32x4 acc[4];
    #pragma unroll
    for (int t = 0; t < 4; ++t) acc[t] = (f32x4){0.f, 0.f, 0.f, 0.f};

    for (int kt = 0; kt < NTL; ++kt) {
        if (kt + 1 < NTL) STAGE_B(kt + 1, (kt + 1) & 1);
        const char* bbase = BbC + (kt & 1) * (512 * KT * 2);
        #pragma unroll
        for (int ksl = 0; ksl < 2; ++ksl) {
            const int ks = kt * 2 + ksl;
            s16x8 a = *(const s16x8*)((char*)Ab + l15 * 1024 +
                                      (((lg + ks * 4) ^ (l15 & 7)) << 4));
            #pragma unroll
            for (int t = 0; t < 4; ++t) {
                const int c = wv * 64 + t * 16 + l15;   // c&7 == l15&7
                s16x8 bf = *(const s16x8*)(bbase + c * 128 +
                                           (((lg + ksl * 4) ^ (l15 & 7)) << 4));
                acc[t] = __builtin_amdgcn_mfma_f32_16x16x32_bf16(a, bf, acc[t], 0, 0, 0);
            }
        }
        __syncthreads();
    }

    // ---- Epilogue (verified R5/R9). C/D: col = l15 (within tile), row = lg*4 + r ----
    float bv[4];
    #pragma unroll
    for (int t = 0; t < 4; ++t) bv[t] = bias[wv * 64 + t * 16 + l15];
    float z[4][4];
    #pragma unroll
    for (int r = 0; r < 4; ++r)
        #pragma unroll
        for (int t = 0; t < 4; ++t) z[r][t] = acc[t][r] + bv[t];

    #pragma unroll
    for (int r = 0; r < 4; ++r) {
        float vm = fmaxf(fmaxf(z[r][0], z[r][1]), fmaxf(z[r][2], z[r][3]));
        #pragma unroll
        for (int off = 1; off < 16; off <<= 1) vm = fmaxf(vm, __shfl_xor(vm, off, 64));
        if (l15 == 0) lmax[(lg * 4 + r) * 8 + wv] = vm;
    }
    __syncthreads();

    float e[4][4];
    #pragma unroll
    for (int r = 0; r < 4; ++r) {
        const int m = lg * 4 + r;
        float vm = lmax[m * 8];
        #pragma unroll
        for (int w = 1; w < 8; ++w) vm = fmaxf(vm, lmax[m * 8 + w]);
        float sv = 0.f;
        #pragma unroll
        for (int t = 0; t < 4; ++t) { e[r][t] = __expf(z[r][t] - vm); sv += e[r][t]; }
        #pragma unroll
        for (int off = 1; off < 16; off <<= 1) sv += __shfl_xor(sv, off, 64);
        if (l15 == 0) lsum[m * 8 + wv] = sv;
    }
    __syncthreads();

    #pragma unroll
    for (int r = 0; r < 4; ++r) {
        const int m = lg * 4 + r;
        float dv = 0.f;
        #pragma unroll
        for (int w = 0; w < 8; ++w) dv += lsum[m * 8 + w];
        const float inv = 1.0f / dv;
        float gs = 0.f;
        #pragma unroll
        for (int t = 0; t < 4; ++t) {
            float g = e[r][t] * inv - y[(size_t)(s0 + m) * Cn + wv * 64 + t * 16 + l15];
            gs += g * g;
        }
        #pragma unroll
        for (int off = 1; off < 16; off <<= 1) gs += __shfl_xor(gs, off, 64);
        if (l15 == 0) lgsq[m * 8 + wv] = gs;
    }
    __syncthreads();

    if (tid < 16) {
        float gsq = 0.f;
        #pragma unroll
        for (int w = 0; w < 8; ++w) gsq += lgsq[tid * 8 + w];
        // ||gW||_F^2 + ||gb||^2 = (||x||^2 + 1) * ||g||^2
        out[s0 + tid] = sqrtf((xn2s[tid] + 1.0f) * gsq);
    }
}

extern "C" void kernel_launch(void* const* d_in, const int* in_sizes, int n_in,
                              void* d_out, int out_size, void* d_ws, size_t ws_size,
                              hipStream_t stream) {
    const float* x  = (const float*)d_in[0];
    const float* y  = (const float*)d_in[1];
    const float* W  = (const float*)d_in[2];
    const float* b  = (const float*)d_in[3];
    float* out = (float*)d_out;

    unsigned short* wt = (unsigned short*)d_ws;                  // 512 KB bf16 W^T
    unsigned* cnt = (unsigned*)((char*)d_ws + (1 << 20));        // barrier counter @ 1 MB

    gnorm_fused<<<dim3(NBLK), dim3(512), 0, stream>>>(x, W, y, b, out, wt, cnt);
}